// Round 5
// baseline (321.301 us; speedup 1.0000x reference)
//
#include <hip/hip_runtime.h>
#include <hip/hip_bf16.h>

#define B_  2
#define L_  2048
#define HS_ 2048
#define NH_ 16
#define NKV_ 4
#define HD_ 128
#define EPS_ 1e-6f
#define SCALE_ 0.08838834764831843f
#define LOG2E_ 1.4426950408889634f

typedef __attribute__((ext_vector_type(8))) short bf16x8;
typedef __attribute__((ext_vector_type(4))) float f32x4;

__device__ __forceinline__ f32x4 mfma16(bf16x8 a, bf16x8 b, f32x4 c) {
    return __builtin_amdgcn_mfma_f32_16x16x32_bf16(a, b, c, 0, 0, 0);
}

__device__ __forceinline__ void async_copy16(void* lds, const void* g) {
    __builtin_amdgcn_global_load_lds(
        (const __attribute__((address_space(1))) unsigned int*)g,
        (__attribute__((address_space(3))) unsigned int*)lds,
        16, 0, 0);
}

// Single-instruction RNE f32 pair -> packed bf16.
__device__ __forceinline__ unsigned cvtpk(float lo, float hi) {
    unsigned r;
    asm("v_cvt_pk_bf16_f32 %0, %1, %2" : "=v"(r) : "v"(lo), "v"(hi));
    return r;
}

// ---------------------------------------------------------------------------
__global__ __launch_bounds__(256) void cvt_f32_bf16(const float* __restrict__ src,
                                                    __hip_bfloat16* __restrict__ dst,
                                                    int n4) {
    int i = blockIdx.x * 256 + threadIdx.x;
    if (i >= n4) return;
    float4 v = ((const float4*)src)[i];
    union { __hip_bfloat16 h[4]; short4 s; } u;
    u.h[0] = __float2bfloat16(v.x);
    u.h[1] = __float2bfloat16(v.y);
    u.h[2] = __float2bfloat16(v.z);
    u.h[3] = __float2bfloat16(v.w);
    ((short4*)dst)[i] = u.s;
}

// ---------------------------------------------------------------------------
__global__ __launch_bounds__(256) void transpose_cvt(const float* __restrict__ src,
                                                     __hip_bfloat16* __restrict__ dst,
                                                     int K, int N) {
    __shared__ float tile[32][33];
    int n0 = blockIdx.x * 32, k0 = blockIdx.y * 32;
    int tx = threadIdx.x & 31, ty = threadIdx.x >> 5;
#pragma unroll
    for (int i = 0; i < 32; i += 8)
        tile[ty + i][tx] = src[(size_t)(k0 + ty + i) * N + n0 + tx];
    __syncthreads();
#pragma unroll
    for (int i = 0; i < 32; i += 8)
        dst[(size_t)(n0 + ty + i) * K + k0 + tx] = __float2bfloat16(tile[tx][ty + i]);
}

// ---------------------------------------------------------------------------
// V slice of kv_f32 [M,1024] (cols 512+kv*128+d) -> Vt [B,NKV,HD,L] bf16
__global__ __launch_bounds__(256) void v_transpose(const float* __restrict__ KV,
                                                   __hip_bfloat16* __restrict__ Vt) {
    __shared__ float tile[32][33];
    int bkv = blockIdx.z;
    int b = bkv >> 2, kv = bkv & 3;
    int l0 = blockIdx.x * 32, d0 = blockIdx.y * 32;
    int tx = threadIdx.x & 31, ty = threadIdx.x >> 5;
#pragma unroll
    for (int i = 0; i < 32; i += 8)
        tile[ty + i][tx] = KV[(size_t)(b * L_ + l0 + ty + i) * 1024 + 512 + kv * HD_ + d0 + tx];
    __syncthreads();
#pragma unroll
    for (int i = 0; i < 32; i += 8)
        Vt[((size_t)(b * NKV_ + kv) * HD_ + d0 + ty + i) * L_ + l0 + tx] =
            __float2bfloat16(tile[tx][ty + i]);
}

// ---------------------------------------------------------------------------
// 256x256 8-phase GEMM (unchanged, verified). K=2048.
#define GNT 32
#define GKB 4096   // K=2048 * 2B row stride
__global__ __launch_bounds__(512, 2) void gemm8_bf16(const __hip_bfloat16* __restrict__ A,
                                                     const __hip_bfloat16* __restrict__ Bt,
                                                     float* __restrict__ C1,
                                                     float* __restrict__ C2,
                                                     int Ntot, int splitN) {
    __shared__ __align__(16) char lds[131072];
    int t = threadIdx.x;
    int w = t >> 6, lane = t & 63;
    int row16 = lane & 15, quad = lane >> 4, e7 = row16 & 7;
    int wr = w >> 2, wc = w & 3;

    int gx = gridDim.x;
    int nwg = gx * gridDim.y;
    int bid = blockIdx.y * gx + blockIdx.x;
    int cpx = nwg >> 3;
    int swz = (bid & 7) * cpx + (bid >> 3);
    int bx = swz % gx, by = swz / gx;
    int m0 = bx * 256, n0 = by * 256;

    const char* baseA[2];
    const char* baseB[2];
#pragma unroll
    for (int kc = 0; kc < 2; ++kc) {
        int so = ((kc * 4 + quad) ^ e7) << 4;
        baseA[kc] = lds + wr * 16384 + row16 * 128 + so;
        baseB[kc] = lds + 65536 + wc * 8192 + row16 * 128 + so;
    }

    int r8 = lane >> 3;
    int sl = (lane & 7) ^ r8;
    char* dstA = lds + wr * 16384 + (w & 3) * 2048 + lane * 16;
    char* dstB = lds + 65536 + (w >> 1) * 8192 + (w & 1) * 2048 + lane * 16;
    const char* gA = (const char*)A +
        (size_t)(m0 + wr * 128 + (w & 3) * 16 + r8) * GKB + sl * 16;
    const char* gB = (const char*)Bt +
        (size_t)(n0 + (w >> 1) * 64 + (w & 1) * 16 + r8) * GKB + sl * 16;

    f32x4 acc[8][4] = {};
    bf16x8 a[4][2], b[2][2];

#pragma unroll
    for (int i = 0; i < 2; ++i) async_copy16(dstA + i * 1024, gA + i * 32768);
#pragma unroll
    for (int i = 0; i < 2; ++i) async_copy16(dstB + i * 1024, gB + i * 32768);
#pragma unroll
    for (int i = 0; i < 2; ++i) async_copy16(dstB + 4096 + i * 1024, gB + 131072 + i * 32768);
#pragma unroll
    for (int i = 0; i < 2; ++i) async_copy16(dstA + 8192 + i * 1024, gA + 262144 + i * 32768);

    for (int Tb = 0; Tb < GNT; Tb += 2) {
#pragma unroll
        for (int u = 0; u < 2; ++u) {
            const int T = Tb + u;
            const int cu = u * 32768, du = (u ^ 1) * 32768;
            const int tn = (T + 1 < GNT ? T + 1 : T) * 128;

            asm volatile("s_waitcnt vmcnt(4)" ::: "memory");
            __builtin_amdgcn_s_barrier();
            __builtin_amdgcn_sched_barrier(0);
#pragma unroll
            for (int mi = 0; mi < 4; ++mi)
#pragma unroll
                for (int kc = 0; kc < 2; ++kc)
                    a[mi][kc] = *(const bf16x8*)(baseA[kc] + cu + mi * 2048);
#pragma unroll
            for (int ni = 0; ni < 2; ++ni)
#pragma unroll
                for (int kc = 0; kc < 2; ++kc)
                    b[ni][kc] = *(const bf16x8*)(baseB[kc] + cu + ni * 2048);
#pragma unroll
            for (int i = 0; i < 2; ++i)
                async_copy16(dstA + du + i * 1024, gA + tn + i * 32768);
            asm volatile("s_waitcnt lgkmcnt(0)" ::: "memory");
            __builtin_amdgcn_sched_barrier(0);
            __builtin_amdgcn_s_setprio(1);
#pragma unroll
            for (int mi = 0; mi < 4; ++mi)
#pragma unroll
                for (int ni = 0; ni < 2; ++ni)
#pragma unroll
                    for (int kc = 0; kc < 2; ++kc)
                        acc[mi][ni] = mfma16(a[mi][kc], b[ni][kc], acc[mi][ni]);
            __builtin_amdgcn_s_setprio(0);

            asm volatile("s_waitcnt vmcnt(4)" ::: "memory");
            __builtin_amdgcn_s_barrier();
            __builtin_amdgcn_sched_barrier(0);
#pragma unroll
            for (int ni = 0; ni < 2; ++ni)
#pragma unroll
                for (int kc = 0; kc < 2; ++kc)
                    b[ni][kc] = *(const bf16x8*)(baseB[kc] + cu + 4096 + ni * 2048);
#pragma unroll
            for (int i = 0; i < 2; ++i)
                async_copy16(dstB + du + i * 1024, gB + tn + i * 32768);
            asm volatile("s_waitcnt lgkmcnt(0)" ::: "memory");
            __builtin_amdgcn_sched_barrier(0);
            __builtin_amdgcn_s_setprio(1);
#pragma unroll
            for (int mi = 0; mi < 4; ++mi)
#pragma unroll
                for (int ni = 0; ni < 2; ++ni)
#pragma unroll
                    for (int kc = 0; kc < 2; ++kc)
                        acc[mi][2 + ni] = mfma16(a[mi][kc], b[ni][kc], acc[mi][2 + ni]);
            __builtin_amdgcn_s_setprio(0);

            asm volatile("s_waitcnt vmcnt(4)" ::: "memory");
            __builtin_amdgcn_s_barrier();
            __builtin_amdgcn_sched_barrier(0);
#pragma unroll
            for (int mi = 0; mi < 4; ++mi)
#pragma unroll
                for (int kc = 0; kc < 2; ++kc)
                    a[mi][kc] = *(const bf16x8*)(baseA[kc] + cu + 8192 + mi * 2048);
#pragma unroll
            for (int i = 0; i < 2; ++i)
                async_copy16(dstB + du + 4096 + i * 1024, gB + 131072 + tn + i * 32768);
            asm volatile("s_waitcnt lgkmcnt(0)" ::: "memory");
            __builtin_amdgcn_sched_barrier(0);
            __builtin_amdgcn_s_setprio(1);
#pragma unroll
            for (int mi = 0; mi < 4; ++mi)
#pragma unroll
                for (int ni = 0; ni < 2; ++ni)
#pragma unroll
                    for (int kc = 0; kc < 2; ++kc)
                        acc[4 + mi][2 + ni] = mfma16(a[mi][kc], b[ni][kc], acc[4 + mi][2 + ni]);
            __builtin_amdgcn_s_setprio(0);

            __builtin_amdgcn_s_barrier();
            __builtin_amdgcn_sched_barrier(0);
#pragma unroll
            for (int ni = 0; ni < 2; ++ni)
#pragma unroll
                for (int kc = 0; kc < 2; ++kc)
                    b[ni][kc] = *(const bf16x8*)(baseB[kc] + cu + ni * 2048);
#pragma unroll
            for (int i = 0; i < 2; ++i)
                async_copy16(dstA + du + 8192 + i * 1024, gA + 262144 + tn + i * 32768);
            asm volatile("s_waitcnt lgkmcnt(0)" ::: "memory");
            __builtin_amdgcn_sched_barrier(0);
            __builtin_amdgcn_s_setprio(1);
#pragma unroll
            for (int mi = 0; mi < 4; ++mi)
#pragma unroll
                for (int ni = 0; ni < 2; ++ni)
#pragma unroll
                    for (int kc = 0; kc < 2; ++kc)
                        acc[4 + mi][ni] = mfma16(a[mi][kc], b[ni][kc], acc[4 + mi][ni]);
            __builtin_amdgcn_s_setprio(0);
        }
    }

    float* Cb; int cs, ccol0;
    if (n0 < splitN) { Cb = C1; cs = splitN; ccol0 = n0; }
    else             { Cb = C2; cs = Ntot - splitN; ccol0 = n0 - splitN; }
#pragma unroll
    for (int mi = 0; mi < 8; ++mi)
#pragma unroll
        for (int ni = 0; ni < 4; ++ni) {
            int rbase = m0 + wr * 128 + mi * 16 + quad * 4;
            int col = ccol0 + wc * 64 + ni * 16 + row16;
#pragma unroll
            for (int r = 0; r < 4; ++r)
                Cb[(size_t)(rbase + r) * cs + col] = acc[mi][ni][r];
        }
}

// ---------------------------------------------------------------------------
// 128x256-tile pipelined GEMM for the O-projection (unchanged, verified).
__global__ __launch_bounds__(512, 2) void gemm_o(const __hip_bfloat16* __restrict__ A,
                                                 const __hip_bfloat16* __restrict__ Bt,
                                                 float* __restrict__ C) {
    __shared__ __align__(16) char lds[98304];
    int t = threadIdx.x;
    int w = t >> 6, lane = t & 63;
    int row16 = lane & 15, quad = lane >> 4, e7 = row16 & 15 & 7;
    int wr = w >> 2, wc = w & 3;

    int gx = gridDim.x;
    int nwg = gx * gridDim.y;
    int bid = blockIdx.y * gx + blockIdx.x;
    int cpx = nwg >> 3;
    int swz = (bid & 7) * cpx + (bid >> 3);
    int bx = swz % gx, by = swz / gx;
    int m0 = bx * 128, n0 = by * 256;

    const char* baseA[2];
    const char* baseB[2];
#pragma unroll
    for (int kc = 0; kc < 2; ++kc) {
        int so = ((kc * 4 + quad) ^ e7) << 4;
        baseA[kc] = lds + wr * 8192 + row16 * 128 + so;
        baseB[kc] = lds + 32768 + wc * 8192 + row16 * 128 + so;
    }

    int r8 = lane >> 3;
    int sl = (lane & 7) ^ r8;
    int arow_lo = ((w & 4) << 4) + (w & 3) * 8;
    int li0 = w * 2;
    int brow_lo0 = ((li0) >> 2) * 64 + ((li0) & 3) * 8;
    int brow_lo1 = ((li0 + 1) >> 2) * 64 + ((li0 + 1) & 3) * 8;

    char* dAlo = lds + arow_lo * 128 + lane * 16;
    char* dBlo0 = lds + 32768 + brow_lo0 * 128 + lane * 16;
    char* dBlo1 = lds + 32768 + brow_lo1 * 128 + lane * 16;
    const char* gAlo = (const char*)A + (size_t)(m0 + arow_lo + r8) * GKB + sl * 16;
    const char* gBlo0 = (const char*)Bt + (size_t)(n0 + brow_lo0 + r8) * GKB + sl * 16;
    const char* gBlo1 = (const char*)Bt + (size_t)(n0 + brow_lo1 + r8) * GKB + sl * 16;
    const int HI_L = 32 * 128;
    const size_t HI_G = (size_t)32 * GKB;

    f32x4 acc[4][4] = {};
    bf16x8 a[2][2], b[2][2];

    async_copy16(dAlo, gAlo);
    async_copy16(dBlo0, gBlo0);
    async_copy16(dBlo1, gBlo1);
    async_copy16(dBlo0 + HI_L, gBlo0 + HI_G);
    async_copy16(dBlo1 + HI_L, gBlo1 + HI_G);
    async_copy16(dAlo + HI_L, gAlo + HI_G);

    for (int Tb = 0; Tb < GNT; Tb += 2) {
#pragma unroll
        for (int u = 0; u < 2; ++u) {
            const int T = Tb + u;
            const int cuA = u * 16384, duA = (u ^ 1) * 16384;
            const int cuB = u * 32768, duB = (u ^ 1) * 32768;
            const int tn = (T + 1 < GNT ? T + 1 : T) * 128;

            asm volatile("s_waitcnt vmcnt(3)" ::: "memory");
            __builtin_amdgcn_s_barrier();
            __builtin_amdgcn_sched_barrier(0);
#pragma unroll
            for (int mi = 0; mi < 2; ++mi)
#pragma unroll
                for (int kc = 0; kc < 2; ++kc)
                    a[mi][kc] = *(const bf16x8*)(baseA[kc] + cuA + mi * 2048);
#pragma unroll
            for (int ni = 0; ni < 2; ++ni)
#pragma unroll
                for (int kc = 0; kc < 2; ++kc)
                    b[ni][kc] = *(const bf16x8*)(baseB[kc] + cuB + ni * 2048);
            async_copy16(dAlo + duA, gAlo + tn);
            asm volatile("s_waitcnt lgkmcnt(0)" ::: "memory");
            __builtin_amdgcn_sched_barrier(0);
            __builtin_amdgcn_s_setprio(1);
#pragma unroll
            for (int mi = 0; mi < 2; ++mi)
#pragma unroll
                for (int ni = 0; ni < 2; ++ni)
#pragma unroll
                    for (int kc = 0; kc < 2; ++kc)
                        acc[mi][ni] = mfma16(a[mi][kc], b[ni][kc], acc[mi][ni]);
            __builtin_amdgcn_s_setprio(0);

            asm volatile("s_waitcnt vmcnt(2)" ::: "memory");
            __builtin_amdgcn_s_barrier();
            __builtin_amdgcn_sched_barrier(0);
#pragma unroll
            for (int ni = 0; ni < 2; ++ni)
#pragma unroll
                for (int kc = 0; kc < 2; ++kc)
                    b[ni][kc] = *(const bf16x8*)(baseB[kc] + cuB + 4096 + ni * 2048);
            async_copy16(dBlo0 + duB, gBlo0 + tn);
            async_copy16(dBlo1 + duB, gBlo1 + tn);
            asm volatile("s_waitcnt lgkmcnt(0)" ::: "memory");
            __builtin_amdgcn_sched_barrier(0);
            __builtin_amdgcn_s_setprio(1);
#pragma unroll
            for (int mi = 0; mi < 2; ++mi)
#pragma unroll
                for (int ni = 0; ni < 2; ++ni)
#pragma unroll
                    for (int kc = 0; kc < 2; ++kc)
                        acc[mi][2 + ni] = mfma16(a[mi][kc], b[ni][kc], acc[mi][2 + ni]);
            __builtin_amdgcn_s_setprio(0);

            asm volatile("s_waitcnt vmcnt(3)" ::: "memory");
            __builtin_amdgcn_s_barrier();
            __builtin_amdgcn_sched_barrier(0);
#pragma unroll
            for (int mi = 0; mi < 2; ++mi)
#pragma unroll
                for (int kc = 0; kc < 2; ++kc)
                    a[mi][kc] = *(const bf16x8*)(baseA[kc] + cuA + 4096 + mi * 2048);
            async_copy16(dBlo0 + HI_L + duB, gBlo0 + HI_G + tn);
            async_copy16(dBlo1 + HI_L + duB, gBlo1 + HI_G + tn);
            asm volatile("s_waitcnt lgkmcnt(0)" ::: "memory");
            __builtin_amdgcn_sched_barrier(0);
            __builtin_amdgcn_s_setprio(1);
#pragma unroll
            for (int mi = 0; mi < 2; ++mi)
#pragma unroll
                for (int ni = 0; ni < 2; ++ni)
#pragma unroll
                    for (int kc = 0; kc < 2; ++kc)
                        acc[2 + mi][2 + ni] = mfma16(a[mi][kc], b[ni][kc], acc[2 + mi][2 + ni]);
            __builtin_amdgcn_s_setprio(0);

            __builtin_amdgcn_s_barrier();
            __builtin_amdgcn_sched_barrier(0);
#pragma unroll
            for (int ni = 0; ni < 2; ++ni)
#pragma unroll
                for (int kc = 0; kc < 2; ++kc)
                    b[ni][kc] = *(const bf16x8*)(baseB[kc] + cuB + ni * 2048);
            async_copy16(dAlo + HI_L + duA, gAlo + HI_G + tn);
            asm volatile("s_waitcnt lgkmcnt(0)" ::: "memory");
            __builtin_amdgcn_sched_barrier(0);
            __builtin_amdgcn_s_setprio(1);
#pragma unroll
            for (int mi = 0; mi < 2; ++mi)
#pragma unroll
                for (int ni = 0; ni < 2; ++ni)
#pragma unroll
                    for (int kc = 0; kc < 2; ++kc)
                        acc[2 + mi][ni] = mfma16(a[mi][kc], b[ni][kc], acc[2 + mi][ni]);
            __builtin_amdgcn_s_setprio(0);
        }
    }
    asm volatile("s_waitcnt vmcnt(0)" ::: "memory");

#pragma unroll
    for (int mi = 0; mi < 4; ++mi)
#pragma unroll
        for (int ni = 0; ni < 4; ++ni) {
            int rbase = m0 + wr * 64 + mi * 16 + quad * 4;
            int col = n0 + wc * 64 + ni * 16 + row16;
#pragma unroll
            for (int r = 0; r < 4; ++r)
                C[(size_t)(rbase + r) * 2048 + col] = acc[mi][ni][r];
        }
}

// ---------------------------------------------------------------------------
__global__ __launch_bounds__(256) void norm_rope(const float* __restrict__ X,
                                                 __hip_bfloat16* __restrict__ Y,
                                                 const float* __restrict__ w,
                                                 int log2nh, int in_stride, float oscale) {
    int row = blockIdx.x * 4 + (threadIdx.x >> 6);
    int lane = threadIdx.x & 63;
    int m = row >> log2nh;
    int head = row & ((1 << log2nh) - 1);
    int pos = m & (L_ - 1);
    const float* x = X + (size_t)m * in_stride + head * HD_;
    float x1 = x[lane], x2 = x[lane + 64];
    float ss = x1 * x1 + x2 * x2;
#pragma unroll
    for (int mm = 1; mm < 64; mm <<= 1) ss += __shfl_xor(ss, mm);
    float rms = rsqrtf(ss * (1.0f / 128.0f) + EPS_);
    float xn1 = x1 * rms * w[lane];
    float xn2 = x2 * rms * w[lane + 64];
    float inv_freq = __builtin_exp2f(-(float)lane * 0.20762050593046014f);
    float ang = (float)pos * inv_freq;
    float c = cosf(ang), s = sinf(ang);
    __hip_bfloat16* y = Y + (size_t)row * HD_;
    y[lane]      = __float2bfloat16((xn1 * c - xn2 * s) * oscale);
    y[lane + 64] = __float2bfloat16((xn2 * c + xn1 * s) * oscale);
}

// ---------------------------------------------------------------------------
// Flash attention v9: 2 waves x 32 q-rows (two 16-row groups per wave).
// Every K fragment and V fragment read from LDS feeds BOTH q-groups ->
// K/V LDS traffic per unit work halves vs v8 (the measured bottleneck).
// P goes through the per-wave sP serially: pack/write P0 -> read pf0 to
// regs -> overwrite with P1 -> read pf1 (DS ops from one wave execute in
// order, so the overwrite cannot pass the earlier read). Same uniform
// complement-pair grid as v8: 512 blocks of 128 threads, 33 steps each.
__global__ __launch_bounds__(128, 1) void flash_attn(const __hip_bfloat16* __restrict__ Q,
                                                     const __hip_bfloat16* __restrict__ Kb,
                                                     const __hip_bfloat16* __restrict__ Vt,
                                                     __hip_bfloat16* __restrict__ O) {
    __shared__ __align__(16) __hip_bfloat16 sK[2][64 * 128];   // [key][dim], swizzled
    __shared__ __align__(16) __hip_bfloat16 sV[2][128 * 64];   // [dim][key], swizzled
    __shared__ __align__(16) __hip_bfloat16 sP[2][16 * 72];    // per-wave P, stride 72

    int t = threadIdx.x, wave = t >> 6, lane = t & 63;
    int row16 = lane & 15, quad = lane >> 4;
    int h = blockIdx.y, b = blockIdx.z;
    int kv = h & (NKV_ - 1);
    int x = blockIdx.x;                 // 0..15
    int qtA = x, qtB = 31 - x;          // complement pair of 64-row q-tiles
    int nA = qtA + 1;
    const int nTot = 33;

    int e7 = row16 & 7;
    int kOff[4], vOff[2];
#pragma unroll
    for (int kc = 0; kc < 4; ++kc)
        kOff[kc] = row16 * 256 + (((kc * 4 + quad) ^ e7) * 16);
#pragma unroll
    for (int kc2 = 0; kc2 < 2; ++kc2)
        vOff[kc2] = row16 * 128 + (((kc2 * 4 + quad) ^ e7) * 16);

    const char* sKb = (const char*)&sK[0][0];
    const char* sVb = (const char*)&sV[0][0];
    char* myP = (char*)&sP[wave][0];
    int pW = row16 * 144 + quad * 8;
    int pR = row16 * 144 + quad * 16;

    // staging: 2 waves cover the whole 64x128 K-tile and 128x64 V-tile
    const char* gK[8];
    const char* gV[8];
#pragma unroll
    for (int i = 0; i < 8; ++i) {
        int rk = wave * 32 + i * 4 + quad;            // K row 0..63
        int ck = row16 ^ (rk & 7);
        gK[i] = (const char*)(Kb + ((size_t)(b * L_ + rk) * NKV_ + kv) * HD_ + ck * 8);
        int rv = wave * 64 + i * 8 + (lane >> 3);     // V row (dim) 0..127
        int cv = (lane & 7) ^ (rv & 7);
        gV[i] = (const char*)(Vt + ((size_t)(b * NKV_ + kv) * HD_ + rv) * L_ + cv * 8);
    }
    char* dK = (char*)&sK[0][0] + wave * 8192 + lane * 16;
    char* dV = (char*)&sV[0][0] + wave * 8192 + lane * 16;

    bf16x8 qf[2][4];
    f32x4 accO[2][8];
    float lrow[2];
    int q0w = 0;

    auto loadQ = [&](int qt) {
        q0w = qt * 64 + wave * 32;
#pragma unroll
        for (int qg = 0; qg < 2; ++qg) {
            const __hip_bfloat16* qbase =
                Q + ((size_t)(b * L_ + q0w + qg * 16 + row16) * NH_ + h) * HD_ + quad * 8;
#pragma unroll
            for (int kc = 0; kc < 4; ++kc) qf[qg][kc] = *(const bf16x8*)(qbase + kc * 32);
#pragma unroll
            for (int db = 0; db < 8; ++db) accO[qg][db] = f32x4{0.f, 0.f, 0.f, 0.f};
            lrow[qg] = 0.f;
        }
    };

    auto epilogue = [&]() {
#pragma unroll
        for (int qg = 0; qg < 2; ++qg) {
            float l = lrow[qg];
            l += __shfl_xor(l, 16);
            l += __shfl_xor(l, 32);
            float linv = 1.0f / l;
            __hip_bfloat16* obase =
                O + ((size_t)(b * L_ + q0w + qg * 16 + row16) * NH_ + h) * HD_;
#pragma unroll
            for (int db = 0; db < 8; ++db) {
                union { __hip_bfloat16 h4[4]; short4 s4; } u;
#pragma unroll
                for (int r = 0; r < 4; ++r) u.h4[r] = __float2bfloat16(accO[qg][db][r] * linv);
                *(short4*)(obase + db * 16 + quad * 4) = u.s4;
            }
        }
    };

    auto stage = [&](int s1) {
        int kb64 = (s1 < nA ? s1 : s1 - nA) * 64;
        int buf = (s1 & 1) * 16384;
        int ko = kb64 * 1024;
        int vo = kb64 * 2;
#pragma unroll
        for (int i = 0; i < 8; ++i) {
            async_copy16(dK + buf + i * 1024, gK[i] + ko);
            async_copy16(dV + buf + i * 1024, gV[i] + vo);
        }
    };

    loadQ(qtA);
    stage(0);
    for (int s = 0; s < nTot; ++s) {
        __syncthreads();                  // staging s visible; compute s-1 done
        if (s + 1 < nTot) stage(s + 1);
        if (s == nA) { epilogue(); loadQ(qtB); }   // pass boundary (wave-uniform)
        int kcur = (s < nA ? s : s - nA) * 64;
        const char* cK = sKb + (s & 1) * 16384;
        const char* cV = sVb + (s & 1) * 16384;

        // ---- S^T = K Q^T for both q-groups; each kf read feeds 2 MFMAs
        f32x4 st[2][4];
        __builtin_amdgcn_s_setprio(1);
#pragma unroll
        for (int kb = 0; kb < 4; ++kb) {
            bf16x8 kf[4];
#pragma unroll
            for (int kc = 0; kc < 4; ++kc)
                kf[kc] = *(const bf16x8*)(cK + kb * 4096 + kOff[kc]);
#pragma unroll
            for (int qg = 0; qg < 2; ++qg) {
                f32x4 acc = {};
#pragma unroll
                for (int kc = 0; kc < 4; ++kc)
                    acc = mfma16(kf[kc], qf[qg][kc], acc);
                st[qg][kb] = acc;
            }
        }
        __builtin_amdgcn_s_setprio(0);

        // ---- no-max softmax per group
        float p[2][4][4];
        if (kcur + 63 > q0w) {            // diagonal region for this wave
#pragma unroll
            for (int qg = 0; qg < 2; ++qg) {
                int qgRel = q0w + qg * 16 + row16 - kcur - quad * 4;
#pragma unroll
                for (int kb = 0; kb < 4; ++kb)
#pragma unroll
                    for (int r = 0; r < 4; ++r) {
                        float e = __builtin_exp2f(st[qg][kb][r]);
                        p[qg][kb][r] = (kb * 16 + r <= qgRel) ? e : 0.f;
                    }
            }
        } else {
#pragma unroll
            for (int qg = 0; qg < 2; ++qg)
#pragma unroll
                for (int kb = 0; kb < 4; ++kb)
#pragma unroll
                    for (int r = 0; r < 4; ++r)
                        p[qg][kb][r] = __builtin_exp2f(st[qg][kb][r]);
        }
#pragma unroll
        for (int qg = 0; qg < 2; ++qg)
#pragma unroll
            for (int kb = 0; kb < 4; ++kb)
#pragma unroll
                for (int r = 0; r < 4; ++r) lrow[qg] += p[qg][kb][r];

        // ---- P0 -> sP -> pf0 regs; then P1 -> sP (same slots) -> pf1 regs.
        // DS ops from one wave are processed in order: the P1 writes cannot
        // overtake the pf0 reads issued before them.
        bf16x8 pf0[2], pf1[2];
#pragma unroll
        for (int kb = 0; kb < 4; ++kb) {
            uint2 u;
            u.x = cvtpk(p[0][kb][0], p[0][kb][1]);
            u.y = cvtpk(p[0][kb][2], p[0][kb][3]);
            *(uint2*)(myP + pW + kb * 32) = u;
        }
        asm volatile("s_waitcnt lgkmcnt(0)" ::: "memory");
        pf0[0] = *(const bf16x8*)(myP + pR);
        pf0[1] = *(const bf16x8*)(myP + pR + 64);
#pragma unroll
        for (int kb = 0; kb < 4; ++kb) {
            uint2 u;
            u.x = cvtpk(p[1][kb][0], p[1][kb][1]);
            u.y = cvtpk(p[1][kb][2], p[1][kb][3]);
            *(uint2*)(myP + pW + kb * 32) = u;
        }
        asm volatile("s_waitcnt lgkmcnt(0)" ::: "memory");
        pf1[0] = *(const bf16x8*)(myP + pR);
        pf1[1] = *(const bf16x8*)(myP + pR + 64);

        // ---- O^T += V^T P^T; each vf read feeds 2 MFMAs
        __builtin_amdgcn_s_setprio(1);
#pragma unroll
        for (int db = 0; db < 8; ++db) {
#pragma unroll
            for (int kc2 = 0; kc2 < 2; ++kc2) {
                bf16x8 vf = *(const bf16x8*)(cV + db * 2048 + vOff[kc2]);
                accO[0][db] = mfma16(vf, pf0[kc2], accO[0][db]);
                accO[1][db] = mfma16(vf, pf1[kc2], accO[1][db]);
            }
        }
        __builtin_amdgcn_s_setprio(0);
    }
    epilogue();
}

// ---------------------------------------------------------------------------
extern "C" void kernel_launch(void* const* d_in, const int* in_sizes, int n_in,
                              void* d_out, int out_size, void* d_ws, size_t ws_size,
                              hipStream_t stream) {
    const float* hidden = (const float*)d_in[0];
    const float* Wq = (const float*)d_in[1];
    const float* Wk = (const float*)d_in[2];
    const float* Wv = (const float*)d_in[3];
    const float* Wo = (const float*)d_in[4];
    const float* qw = (const float*)d_in[5];
    const float* kw = (const float*)d_in[6];
    float* out = (float*)d_out;

    char* ws = (char*)d_ws;
    size_t off = 0;
    auto alloc = [&](size_t bytes) { char* p = ws + off; off += (bytes + 255) & ~255ull; return p; };
    __hip_bfloat16* Wq_t = (__hip_bfloat16*)alloc((size_t)HS_ * NH_ * HD_ * 2);   // 8 MB
    __hip_bfloat16* Wk_t = (__hip_bfloat16*)alloc((size_t)HS_ * NKV_ * HD_ * 2);  // 2 MB (contiguous after Wq_t)
    __hip_bfloat16* Wv_t = (__hip_bfloat16*)alloc((size_t)HS_ * NKV_ * HD_ * 2);  // 2 MB (contiguous after Wk_t)
    __hip_bfloat16* Wo_t = (__hip_bfloat16*)alloc((size_t)HS_ * NH_ * HD_ * 2);   // 8 MB
    __hip_bfloat16* A_h  = (__hip_bfloat16*)alloc((size_t)B_ * L_ * HS_ * 2);     // 16 MB; reused as attn_bf
    float* kv_f32 = (float*)alloc((size_t)B_ * L_ * 1024 * 4);                    // 16 MB [M,1024] = K|V
    __hip_bfloat16* q_bf  = (__hip_bfloat16*)alloc((size_t)B_ * L_ * NH_ * HD_ * 2);
    __hip_bfloat16* k_bf  = (__hip_bfloat16*)alloc((size_t)B_ * L_ * NKV_ * HD_ * 2);
    __hip_bfloat16* vt_bf = (__hip_bfloat16*)alloc((size_t)B_ * NKV_ * HD_ * L_ * 2);
    float* q_f32 = out;                     // reuse d_out as pre-norm Q scratch
    __hip_bfloat16* attn_bf = A_h;

    const int M = B_ * L_;

    cvt_f32_bf16<<<(M * HS_ / 4 + 255) / 256, 256, 0, stream>>>(hidden, A_h, M * HS_ / 4);
    transpose_cvt<<<dim3(2048 / 32, 2048 / 32), 256, 0, stream>>>(Wq, Wq_t, HS_, 2048);
    transpose_cvt<<<dim3(512 / 32, 2048 / 32), 256, 0, stream>>>(Wk, Wk_t, HS_, 512);
    transpose_cvt<<<dim3(512 / 32, 2048 / 32), 256, 0, stream>>>(Wv, Wv_t, HS_, 512);
    transpose_cvt<<<dim3(2048 / 32, 2048 / 32), 256, 0, stream>>>(Wo, Wo_t, HS_, 2048);
    // fused QKV projection: Bt rows 0..2047 = Wq_t, 2048..2559 = Wk_t, 2560..3071 = Wv_t
    gemm8_bf16<<<dim3(M / 256, 3072 / 256), 512, 0, stream>>>(
        A_h, Wq_t, q_f32, kv_f32, 3072, 2048);
    norm_rope<<<(M * NH_) / 4, 256, 0, stream>>>(q_f32, q_bf, qw, 4, 2048, SCALE_ * LOG2E_);
    norm_rope<<<(M * NKV_) / 4, 256, 0, stream>>>(kv_f32, k_bf, kw, 2, 1024, 1.0f);
    v_transpose<<<dim3(L_ / 32, HD_ / 32, B_ * NKV_), 256, 0, stream>>>(kv_f32, vt_bf);
    flash_attn<<<dim3(16, NH_, B_), 128, 0, stream>>>(q_bf, k_bf, vt_bf, attn_bf);
    gemm_o<<<dim3(M / 128, 2048 / 256), 512, 0, stream>>>(attn_bf, Wo_t, out);
}

// Round 6
// 291.546 us; speedup vs baseline: 1.1021x; 1.1021x over previous
//
#include <hip/hip_runtime.h>
#include <hip/hip_bf16.h>

#define B_  2
#define L_  2048
#define HS_ 2048
#define NH_ 16
#define NKV_ 4
#define HD_ 128
#define EPS_ 1e-6f
#define SCALE_ 0.08838834764831843f
#define LOG2E_ 1.4426950408889634f

typedef __attribute__((ext_vector_type(8))) short bf16x8;
typedef __attribute__((ext_vector_type(4))) float f32x4;

__device__ __forceinline__ f32x4 mfma16(bf16x8 a, bf16x8 b, f32x4 c) {
    return __builtin_amdgcn_mfma_f32_16x16x32_bf16(a, b, c, 0, 0, 0);
}

__device__ __forceinline__ void async_copy16(void* lds, const void* g) {
    __builtin_amdgcn_global_load_lds(
        (const __attribute__((address_space(1))) unsigned int*)g,
        (__attribute__((address_space(3))) unsigned int*)lds,
        16, 0, 0);
}

// Single-instruction RNE f32 pair -> packed bf16.
__device__ __forceinline__ unsigned cvtpk(float lo, float hi) {
    unsigned r;
    asm("v_cvt_pk_bf16_f32 %0, %1, %2" : "=v"(r) : "v"(lo), "v"(hi));
    return r;
}

// ---------------------------------------------------------------------------
// fused_prep: one launch covering
//   [0, 8192)        : hidden f32 -> bf16 (float4-vectorized)
//   [8192, 12288)    : Wq  [2048,2048] -> Wq_t (transpose + cvt)
//   [12288, 13312)   : Wk  [2048,512]  -> Wk_t
//   [13312, 14336)   : Wv  [2048,512]  -> Wv_t
//   [14336, 18432)   : Wo  [2048,2048] -> Wo_t
__global__ __launch_bounds__(256) void fused_prep(
    const float* __restrict__ hidden, __hip_bfloat16* __restrict__ A_h,
    const float* __restrict__ Wq, __hip_bfloat16* __restrict__ Wq_t,
    const float* __restrict__ Wk, __hip_bfloat16* __restrict__ Wk_t,
    const float* __restrict__ Wv, __hip_bfloat16* __restrict__ Wv_t,
    const float* __restrict__ Wo, __hip_bfloat16* __restrict__ Wo_t) {
    __shared__ float tile[32][33];
    int bid = blockIdx.x;
    if (bid < 8192) {
        int i = bid * 256 + threadIdx.x;
        float4 v = ((const float4*)hidden)[i];
        union { __hip_bfloat16 h[4]; short4 s; } u;
        u.h[0] = __float2bfloat16(v.x);
        u.h[1] = __float2bfloat16(v.y);
        u.h[2] = __float2bfloat16(v.z);
        u.h[3] = __float2bfloat16(v.w);
        ((short4*)A_h)[i] = u.s;
        return;
    }
    const float* src; __hip_bfloat16* dst; int N, tb;
    if (bid < 12288)      { tb = bid - 8192;  src = Wq; dst = Wq_t; N = 2048; }
    else if (bid < 13312) { tb = bid - 12288; src = Wk; dst = Wk_t; N = 512;  }
    else if (bid < 14336) { tb = bid - 13312; src = Wv; dst = Wv_t; N = 512;  }
    else                  { tb = bid - 14336; src = Wo; dst = Wo_t; N = 2048; }
    int nt = N >> 5;
    int n0 = (tb % nt) * 32, k0 = (tb / nt) * 32;
    int tx = threadIdx.x & 31, ty = threadIdx.x >> 5;
#pragma unroll
    for (int i = 0; i < 32; i += 8)
        tile[ty + i][tx] = src[(size_t)(k0 + ty + i) * N + n0 + tx];
    __syncthreads();
#pragma unroll
    for (int i = 0; i < 32; i += 8)
        dst[(size_t)(n0 + ty + i) * HS_ + k0 + tx] = __float2bfloat16(tile[tx][ty + i]);
}

// ---------------------------------------------------------------------------
// fused_norm_v: one launch covering
//   [0, 16384)       : norm_rope on Q rows (log2nh=4, stride 2048, oscale SCALE*LOG2E)
//   [16384, 20480)   : norm_rope on K rows (log2nh=2, stride 1024, oscale 1)
//   [20480, 22528)   : v_transpose (kv_f32 V-half -> Vt bf16)
__device__ __forceinline__ void norm_rope_row(const float* __restrict__ X,
                                              __hip_bfloat16* __restrict__ Y,
                                              const float* __restrict__ w,
                                              int row, int lane,
                                              int log2nh, int in_stride, float oscale) {
    int m = row >> log2nh;
    int head = row & ((1 << log2nh) - 1);
    int pos = m & (L_ - 1);
    const float* x = X + (size_t)m * in_stride + head * HD_;
    float x1 = x[lane], x2 = x[lane + 64];
    float ss = x1 * x1 + x2 * x2;
#pragma unroll
    for (int mm = 1; mm < 64; mm <<= 1) ss += __shfl_xor(ss, mm);
    float rms = rsqrtf(ss * (1.0f / 128.0f) + EPS_);
    float xn1 = x1 * rms * w[lane];
    float xn2 = x2 * rms * w[lane + 64];
    float inv_freq = __builtin_exp2f(-(float)lane * 0.20762050593046014f);
    float ang = (float)pos * inv_freq;
    float c = cosf(ang), s = sinf(ang);
    __hip_bfloat16* y = Y + (size_t)row * HD_;
    y[lane]      = __float2bfloat16((xn1 * c - xn2 * s) * oscale);
    y[lane + 64] = __float2bfloat16((xn2 * c + xn1 * s) * oscale);
}

__global__ __launch_bounds__(256) void fused_norm_v(
    const float* __restrict__ q_f32, __hip_bfloat16* __restrict__ q_bf,
    const float* __restrict__ kv_f32, __hip_bfloat16* __restrict__ k_bf,
    __hip_bfloat16* __restrict__ vt_bf,
    const float* __restrict__ qw, const float* __restrict__ kw) {
    __shared__ float tile[32][33];
    int bid = blockIdx.x;
    int lane = threadIdx.x & 63;
    if (bid < 16384) {
        int row = bid * 4 + (threadIdx.x >> 6);
        norm_rope_row(q_f32, q_bf, qw, row, lane, 4, 2048, SCALE_ * LOG2E_);
        return;
    }
    if (bid < 20480) {
        int row = (bid - 16384) * 4 + (threadIdx.x >> 6);
        norm_rope_row(kv_f32, k_bf, kw, row, lane, 2, 1024, 1.0f);
        return;
    }
    int vbid = bid - 20480;                     // grid was (64, 4, 8)
    int xb = vbid & 63, yb = (vbid >> 6) & 3, zb = vbid >> 8;
    int b = zb >> 2, kv = zb & 3;
    int l0 = xb * 32, d0 = yb * 32;
    int tx = threadIdx.x & 31, ty = threadIdx.x >> 5;
#pragma unroll
    for (int i = 0; i < 32; i += 8)
        tile[ty + i][tx] = kv_f32[(size_t)(b * L_ + l0 + ty + i) * 1024 + 512 + kv * HD_ + d0 + tx];
    __syncthreads();
#pragma unroll
    for (int i = 0; i < 32; i += 8)
        vt_bf[((size_t)(b * NKV_ + kv) * HD_ + d0 + ty + i) * L_ + l0 + tx] =
            __float2bfloat16(tile[tx][ty + i]);
}

// ---------------------------------------------------------------------------
// 256x256 8-phase GEMM (unchanged, verified). K=2048.
#define GNT 32
#define GKB 4096   // K=2048 * 2B row stride
__global__ __launch_bounds__(512, 2) void gemm8_bf16(const __hip_bfloat16* __restrict__ A,
                                                     const __hip_bfloat16* __restrict__ Bt,
                                                     float* __restrict__ C1,
                                                     float* __restrict__ C2,
                                                     int Ntot, int splitN) {
    __shared__ __align__(16) char lds[131072];
    int t = threadIdx.x;
    int w = t >> 6, lane = t & 63;
    int row16 = lane & 15, quad = lane >> 4, e7 = row16 & 7;
    int wr = w >> 2, wc = w & 3;

    int gx = gridDim.x;
    int nwg = gx * gridDim.y;
    int bid = blockIdx.y * gx + blockIdx.x;
    int cpx = nwg >> 3;
    int swz = (bid & 7) * cpx + (bid >> 3);
    int bx = swz % gx, by = swz / gx;
    int m0 = bx * 256, n0 = by * 256;

    const char* baseA[2];
    const char* baseB[2];
#pragma unroll
    for (int kc = 0; kc < 2; ++kc) {
        int so = ((kc * 4 + quad) ^ e7) << 4;
        baseA[kc] = lds + wr * 16384 + row16 * 128 + so;
        baseB[kc] = lds + 65536 + wc * 8192 + row16 * 128 + so;
    }

    int r8 = lane >> 3;
    int sl = (lane & 7) ^ r8;
    char* dstA = lds + wr * 16384 + (w & 3) * 2048 + lane * 16;
    char* dstB = lds + 65536 + (w >> 1) * 8192 + (w & 1) * 2048 + lane * 16;
    const char* gA = (const char*)A +
        (size_t)(m0 + wr * 128 + (w & 3) * 16 + r8) * GKB + sl * 16;
    const char* gB = (const char*)Bt +
        (size_t)(n0 + (w >> 1) * 64 + (w & 1) * 16 + r8) * GKB + sl * 16;

    f32x4 acc[8][4] = {};
    bf16x8 a[4][2], b[2][2];

#pragma unroll
    for (int i = 0; i < 2; ++i) async_copy16(dstA + i * 1024, gA + i * 32768);
#pragma unroll
    for (int i = 0; i < 2; ++i) async_copy16(dstB + i * 1024, gB + i * 32768);
#pragma unroll
    for (int i = 0; i < 2; ++i) async_copy16(dstB + 4096 + i * 1024, gB + 131072 + i * 32768);
#pragma unroll
    for (int i = 0; i < 2; ++i) async_copy16(dstA + 8192 + i * 1024, gA + 262144 + i * 32768);

    for (int Tb = 0; Tb < GNT; Tb += 2) {
#pragma unroll
        for (int u = 0; u < 2; ++u) {
            const int T = Tb + u;
            const int cu = u * 32768, du = (u ^ 1) * 32768;
            const int tn = (T + 1 < GNT ? T + 1 : T) * 128;

            asm volatile("s_waitcnt vmcnt(4)" ::: "memory");
            __builtin_amdgcn_s_barrier();
            __builtin_amdgcn_sched_barrier(0);
#pragma unroll
            for (int mi = 0; mi < 4; ++mi)
#pragma unroll
                for (int kc = 0; kc < 2; ++kc)
                    a[mi][kc] = *(const bf16x8*)(baseA[kc] + cu + mi * 2048);
#pragma unroll
            for (int ni = 0; ni < 2; ++ni)
#pragma unroll
                for (int kc = 0; kc < 2; ++kc)
                    b[ni][kc] = *(const bf16x8*)(baseB[kc] + cu + ni * 2048);
#pragma unroll
            for (int i = 0; i < 2; ++i)
                async_copy16(dstA + du + i * 1024, gA + tn + i * 32768);
            asm volatile("s_waitcnt lgkmcnt(0)" ::: "memory");
            __builtin_amdgcn_sched_barrier(0);
            __builtin_amdgcn_s_setprio(1);
#pragma unroll
            for (int mi = 0; mi < 4; ++mi)
#pragma unroll
                for (int ni = 0; ni < 2; ++ni)
#pragma unroll
                    for (int kc = 0; kc < 2; ++kc)
                        acc[mi][ni] = mfma16(a[mi][kc], b[ni][kc], acc[mi][ni]);
            __builtin_amdgcn_s_setprio(0);

            asm volatile("s_waitcnt vmcnt(4)" ::: "memory");
            __builtin_amdgcn_s_barrier();
            __builtin_amdgcn_sched_barrier(0);
#pragma unroll
            for (int ni = 0; ni < 2; ++ni)
#pragma unroll
                for (int kc = 0; kc < 2; ++kc)
                    b[ni][kc] = *(const bf16x8*)(baseB[kc] + cu + 4096 + ni * 2048);
#pragma unroll
            for (int i = 0; i < 2; ++i)
                async_copy16(dstB + du + i * 1024, gB + tn + i * 32768);
            asm volatile("s_waitcnt lgkmcnt(0)" ::: "memory");
            __builtin_amdgcn_sched_barrier(0);
            __builtin_amdgcn_s_setprio(1);
#pragma unroll
            for (int mi = 0; mi < 4; ++mi)
#pragma unroll
                for (int ni = 0; ni < 2; ++ni)
#pragma unroll
                    for (int kc = 0; kc < 2; ++kc)
                        acc[mi][2 + ni] = mfma16(a[mi][kc], b[ni][kc], acc[mi][2 + ni]);
            __builtin_amdgcn_s_setprio(0);

            asm volatile("s_waitcnt vmcnt(4)" ::: "memory");
            __builtin_amdgcn_s_barrier();
            __builtin_amdgcn_sched_barrier(0);
#pragma unroll
            for (int mi = 0; mi < 4; ++mi)
#pragma unroll
                for (int kc = 0; kc < 2; ++kc)
                    a[mi][kc] = *(const bf16x8*)(baseA[kc] + cu + 8192 + mi * 2048);
#pragma unroll
            for (int i = 0; i < 2; ++i)
                async_copy16(dstB + du + 4096 + i * 1024, gB + 131072 + tn + i * 32768);
            asm volatile("s_waitcnt lgkmcnt(0)" ::: "memory");
            __builtin_amdgcn_sched_barrier(0);
            __builtin_amdgcn_s_setprio(1);
#pragma unroll
            for (int mi = 0; mi < 4; ++mi)
#pragma unroll
                for (int ni = 0; ni < 2; ++ni)
#pragma unroll
                    for (int kc = 0; kc < 2; ++kc)
                        acc[4 + mi][2 + ni] = mfma16(a[mi][kc], b[ni][kc], acc[4 + mi][2 + ni]);
            __builtin_amdgcn_s_setprio(0);

            __builtin_amdgcn_s_barrier();
            __builtin_amdgcn_sched_barrier(0);
#pragma unroll
            for (int ni = 0; ni < 2; ++ni)
#pragma unroll
                for (int kc = 0; kc < 2; ++kc)
                    b[ni][kc] = *(const bf16x8*)(baseB[kc] + cu + ni * 2048);
#pragma unroll
            for (int i = 0; i < 2; ++i)
                async_copy16(dstA + du + 8192 + i * 1024, gA + 262144 + tn + i * 32768);
            asm volatile("s_waitcnt lgkmcnt(0)" ::: "memory");
            __builtin_amdgcn_sched_barrier(0);
            __builtin_amdgcn_s_setprio(1);
#pragma unroll
            for (int mi = 0; mi < 4; ++mi)
#pragma unroll
                for (int ni = 0; ni < 2; ++ni)
#pragma unroll
                    for (int kc = 0; kc < 2; ++kc)
                        acc[4 + mi][ni] = mfma16(a[mi][kc], b[ni][kc], acc[4 + mi][ni]);
            __builtin_amdgcn_s_setprio(0);
        }
    }

    float* Cb; int cs, ccol0;
    if (n0 < splitN) { Cb = C1; cs = splitN; ccol0 = n0; }
    else             { Cb = C2; cs = Ntot - splitN; ccol0 = n0 - splitN; }
#pragma unroll
    for (int mi = 0; mi < 8; ++mi)
#pragma unroll
        for (int ni = 0; ni < 4; ++ni) {
            int rbase = m0 + wr * 128 + mi * 16 + quad * 4;
            int col = ccol0 + wc * 64 + ni * 16 + row16;
#pragma unroll
            for (int r = 0; r < 4; ++r)
                Cb[(size_t)(rbase + r) * cs + col] = acc[mi][ni][r];
        }
}

// ---------------------------------------------------------------------------
// 128x256-tile pipelined GEMM for the O-projection (unchanged, verified).
__global__ __launch_bounds__(512, 2) void gemm_o(const __hip_bfloat16* __restrict__ A,
                                                 const __hip_bfloat16* __restrict__ Bt,
                                                 float* __restrict__ C) {
    __shared__ __align__(16) char lds[98304];
    int t = threadIdx.x;
    int w = t >> 6, lane = t & 63;
    int row16 = lane & 15, quad = lane >> 4, e7 = row16 & 15 & 7;
    int wr = w >> 2, wc = w & 3;

    int gx = gridDim.x;
    int nwg = gx * gridDim.y;
    int bid = blockIdx.y * gx + blockIdx.x;
    int cpx = nwg >> 3;
    int swz = (bid & 7) * cpx + (bid >> 3);
    int bx = swz % gx, by = swz / gx;
    int m0 = bx * 128, n0 = by * 256;

    const char* baseA[2];
    const char* baseB[2];
#pragma unroll
    for (int kc = 0; kc < 2; ++kc) {
        int so = ((kc * 4 + quad) ^ e7) << 4;
        baseA[kc] = lds + wr * 8192 + row16 * 128 + so;
        baseB[kc] = lds + 32768 + wc * 8192 + row16 * 128 + so;
    }

    int r8 = lane >> 3;
    int sl = (lane & 7) ^ r8;
    int arow_lo = ((w & 4) << 4) + (w & 3) * 8;
    int li0 = w * 2;
    int brow_lo0 = ((li0) >> 2) * 64 + ((li0) & 3) * 8;
    int brow_lo1 = ((li0 + 1) >> 2) * 64 + ((li0 + 1) & 3) * 8;

    char* dAlo = lds + arow_lo * 128 + lane * 16;
    char* dBlo0 = lds + 32768 + brow_lo0 * 128 + lane * 16;
    char* dBlo1 = lds + 32768 + brow_lo1 * 128 + lane * 16;
    const char* gAlo = (const char*)A + (size_t)(m0 + arow_lo + r8) * GKB + sl * 16;
    const char* gBlo0 = (const char*)Bt + (size_t)(n0 + brow_lo0 + r8) * GKB + sl * 16;
    const char* gBlo1 = (const char*)Bt + (size_t)(n0 + brow_lo1 + r8) * GKB + sl * 16;
    const int HI_L = 32 * 128;
    const size_t HI_G = (size_t)32 * GKB;

    f32x4 acc[4][4] = {};
    bf16x8 a[2][2], b[2][2];

    async_copy16(dAlo, gAlo);
    async_copy16(dBlo0, gBlo0);
    async_copy16(dBlo1, gBlo1);
    async_copy16(dBlo0 + HI_L, gBlo0 + HI_G);
    async_copy16(dBlo1 + HI_L, gBlo1 + HI_G);
    async_copy16(dAlo + HI_L, gAlo + HI_G);

    for (int Tb = 0; Tb < GNT; Tb += 2) {
#pragma unroll
        for (int u = 0; u < 2; ++u) {
            const int T = Tb + u;
            const int cuA = u * 16384, duA = (u ^ 1) * 16384;
            const int cuB = u * 32768, duB = (u ^ 1) * 32768;
            const int tn = (T + 1 < GNT ? T + 1 : T) * 128;

            asm volatile("s_waitcnt vmcnt(3)" ::: "memory");
            __builtin_amdgcn_s_barrier();
            __builtin_amdgcn_sched_barrier(0);
#pragma unroll
            for (int mi = 0; mi < 2; ++mi)
#pragma unroll
                for (int kc = 0; kc < 2; ++kc)
                    a[mi][kc] = *(const bf16x8*)(baseA[kc] + cuA + mi * 2048);
#pragma unroll
            for (int ni = 0; ni < 2; ++ni)
#pragma unroll
                for (int kc = 0; kc < 2; ++kc)
                    b[ni][kc] = *(const bf16x8*)(baseB[kc] + cuB + ni * 2048);
            async_copy16(dAlo + duA, gAlo + tn);
            asm volatile("s_waitcnt lgkmcnt(0)" ::: "memory");
            __builtin_amdgcn_sched_barrier(0);
            __builtin_amdgcn_s_setprio(1);
#pragma unroll
            for (int mi = 0; mi < 2; ++mi)
#pragma unroll
                for (int ni = 0; ni < 2; ++ni)
#pragma unroll
                    for (int kc = 0; kc < 2; ++kc)
                        acc[mi][ni] = mfma16(a[mi][kc], b[ni][kc], acc[mi][ni]);
            __builtin_amdgcn_s_setprio(0);

            asm volatile("s_waitcnt vmcnt(2)" ::: "memory");
            __builtin_amdgcn_s_barrier();
            __builtin_amdgcn_sched_barrier(0);
#pragma unroll
            for (int ni = 0; ni < 2; ++ni)
#pragma unroll
                for (int kc = 0; kc < 2; ++kc)
                    b[ni][kc] = *(const bf16x8*)(baseB[kc] + cuB + 4096 + ni * 2048);
            async_copy16(dBlo0 + duB, gBlo0 + tn);
            async_copy16(dBlo1 + duB, gBlo1 + tn);
            asm volatile("s_waitcnt lgkmcnt(0)" ::: "memory");
            __builtin_amdgcn_sched_barrier(0);
            __builtin_amdgcn_s_setprio(1);
#pragma unroll
            for (int mi = 0; mi < 2; ++mi)
#pragma unroll
                for (int ni = 0; ni < 2; ++ni)
#pragma unroll
                    for (int kc = 0; kc < 2; ++kc)
                        acc[mi][2 + ni] = mfma16(a[mi][kc], b[ni][kc], acc[mi][2 + ni]);
            __builtin_amdgcn_s_setprio(0);

            asm volatile("s_waitcnt vmcnt(3)" ::: "memory");
            __builtin_amdgcn_s_barrier();
            __builtin_amdgcn_sched_barrier(0);
#pragma unroll
            for (int mi = 0; mi < 2; ++mi)
#pragma unroll
                for (int kc = 0; kc < 2; ++kc)
                    a[mi][kc] = *(const bf16x8*)(baseA[kc] + cuA + 4096 + mi * 2048);
            async_copy16(dBlo0 + HI_L + duB, gBlo0 + HI_G + tn);
            async_copy16(dBlo1 + HI_L + duB, gBlo1 + HI_G + tn);
            asm volatile("s_waitcnt lgkmcnt(0)" ::: "memory");
            __builtin_amdgcn_sched_barrier(0);
            __builtin_amdgcn_s_setprio(1);
#pragma unroll
            for (int mi = 0; mi < 2; ++mi)
#pragma unroll
                for (int ni = 0; ni < 2; ++ni)
#pragma unroll
                    for (int kc = 0; kc < 2; ++kc)
                        acc[2 + mi][2 + ni] = mfma16(a[mi][kc], b[ni][kc], acc[2 + mi][2 + ni]);
            __builtin_amdgcn_s_setprio(0);

            __builtin_amdgcn_s_barrier();
            __builtin_amdgcn_sched_barrier(0);
#pragma unroll
            for (int ni = 0; ni < 2; ++ni)
#pragma unroll
                for (int kc = 0; kc < 2; ++kc)
                    b[ni][kc] = *(const bf16x8*)(baseB[kc] + cuB + ni * 2048);
            async_copy16(dAlo + HI_L + duA, gAlo + HI_G + tn);
            asm volatile("s_waitcnt lgkmcnt(0)" ::: "memory");
            __builtin_amdgcn_sched_barrier(0);
            __builtin_amdgcn_s_setprio(1);
#pragma unroll
            for (int mi = 0; mi < 2; ++mi)
#pragma unroll
                for (int ni = 0; ni < 2; ++ni)
#pragma unroll
                    for (int kc = 0; kc < 2; ++kc)
                        acc[2 + mi][ni] = mfma16(a[mi][kc], b[ni][kc], acc[2 + mi][ni]);
            __builtin_amdgcn_s_setprio(0);
        }
    }
    asm volatile("s_waitcnt vmcnt(0)" ::: "memory");

#pragma unroll
    for (int mi = 0; mi < 4; ++mi)
#pragma unroll
        for (int ni = 0; ni < 4; ++ni) {
            int rbase = m0 + wr * 64 + mi * 16 + quad * 4;
            int col = n0 + wc * 64 + ni * 16 + row16;
#pragma unroll
            for (int r = 0; r < 4; ++r)
                C[(size_t)(rbase + r) * 2048 + col] = acc[mi][ni][r];
        }
}

// ---------------------------------------------------------------------------
// Flash attention v8 (reverted to the verified 4-wave x 16-row structure).
__global__ __launch_bounds__(256, 2) void flash_attn(const __hip_bfloat16* __restrict__ Q,
                                                     const __hip_bfloat16* __restrict__ Kb,
                                                     const __hip_bfloat16* __restrict__ Vt,
                                                     __hip_bfloat16* __restrict__ O) {
    __shared__ __align__(16) __hip_bfloat16 sK[2][64 * 128];
    __shared__ __align__(16) __hip_bfloat16 sV[2][128 * 64];
    __shared__ __align__(16) __hip_bfloat16 sP[4][16 * 72];

    int t = threadIdx.x, wave = t >> 6, lane = t & 63;
    int row16 = lane & 15, quad = lane >> 4;
    int h = blockIdx.y, b = blockIdx.z;
    int kv = h & (NKV_ - 1);
    int x = blockIdx.x;
    int qtA = x, qtB = 31 - x;
    int nA = qtA + 1;
    const int nTot = 33;

    int e7 = row16 & 7;
    int kOff[4], vOff[2];
#pragma unroll
    for (int kc = 0; kc < 4; ++kc)
        kOff[kc] = row16 * 256 + (((kc * 4 + quad) ^ e7) * 16);
#pragma unroll
    for (int kc2 = 0; kc2 < 2; ++kc2)
        vOff[kc2] = row16 * 128 + (((kc2 * 4 + quad) ^ e7) * 16);

    const char* sKb = (const char*)&sK[0][0];
    const char* sVb = (const char*)&sV[0][0];
    char* myP = (char*)&sP[wave][0];
    int pW = row16 * 144 + quad * 8;
    int pR = row16 * 144 + quad * 16;

    const char* gK[4];
    const char* gV[4];
#pragma unroll
    for (int i = 0; i < 4; ++i) {
        int rk = wave * 16 + i * 4 + quad;
        int ck = row16 ^ (rk & 7);
        gK[i] = (const char*)(Kb + ((size_t)(b * L_ + rk) * NKV_ + kv) * HD_ + ck * 8);
        int rv = wave * 32 + i * 8 + (lane >> 3);
        int cv = (lane & 7) ^ (rv & 7);
        gV[i] = (const char*)(Vt + ((size_t)(b * NKV_ + kv) * HD_ + rv) * L_ + cv * 8);
    }
    char* dK = (char*)&sK[0][0] + wave * 4096 + lane * 16;
    char* dV = (char*)&sV[0][0] + wave * 4096 + lane * 16;

    bf16x8 qf[4];
    f32x4 accO[8];
    float lrow;
    int q0w = 0;

    auto loadQ = [&](int qt) {
        q0w = qt * 64 + wave * 16;
        const __hip_bfloat16* qbase =
            Q + ((size_t)(b * L_ + q0w + row16) * NH_ + h) * HD_ + quad * 8;
#pragma unroll
        for (int kc = 0; kc < 4; ++kc) qf[kc] = *(const bf16x8*)(qbase + kc * 32);
#pragma unroll
        for (int db = 0; db < 8; ++db) accO[db] = f32x4{0.f, 0.f, 0.f, 0.f};
        lrow = 0.f;
    };

    auto epilogue = [&]() {
        float l = lrow;
        l += __shfl_xor(l, 16);
        l += __shfl_xor(l, 32);
        float linv = 1.0f / l;
        __hip_bfloat16* obase = O + ((size_t)(b * L_ + q0w + row16) * NH_ + h) * HD_;
#pragma unroll
        for (int db = 0; db < 8; ++db) {
            union { __hip_bfloat16 h4[4]; short4 s4; } u;
#pragma unroll
            for (int r = 0; r < 4; ++r) u.h4[r] = __float2bfloat16(accO[db][r] * linv);
            *(short4*)(obase + db * 16 + quad * 4) = u.s4;
        }
    };

    auto stage = [&](int s1) {
        int kb64 = (s1 < nA ? s1 : s1 - nA) * 64;
        int buf = (s1 & 1) * 16384;
        int ko = kb64 * 1024;
        int vo = kb64 * 2;
#pragma unroll
        for (int i = 0; i < 4; ++i) {
            async_copy16(dK + buf + i * 1024, gK[i] + ko);
            async_copy16(dV + buf + i * 1024, gV[i] + vo);
        }
    };

    loadQ(qtA);
    stage(0);
    for (int s = 0; s < nTot; ++s) {
        __syncthreads();
        if (s + 1 < nTot) stage(s + 1);
        if (s == nA) { epilogue(); loadQ(qtB); }
        int kcur = (s < nA ? s : s - nA) * 64;
        const char* cK = sKb + (s & 1) * 16384;
        const char* cV = sVb + (s & 1) * 16384;

        f32x4 st[4];
        __builtin_amdgcn_s_setprio(1);
#pragma unroll
        for (int kb = 0; kb < 4; ++kb) {
            f32x4 acc = {};
#pragma unroll
            for (int kc = 0; kc < 4; ++kc) {
                bf16x8 kf = *(const bf16x8*)(cK + kb * 4096 + kOff[kc]);
                acc = mfma16(kf, qf[kc], acc);
            }
            st[kb] = acc;
        }
        __builtin_amdgcn_s_setprio(0);

        float p[4][4];
        if (kcur + 63 > q0w) {
            int qgRel = q0w + row16 - kcur - quad * 4;
#pragma unroll
            for (int kb = 0; kb < 4; ++kb)
#pragma unroll
                for (int r = 0; r < 4; ++r) {
                    float e = __builtin_exp2f(st[kb][r]);
                    p[kb][r] = (kb * 16 + r <= qgRel) ? e : 0.f;
                }
        } else {
#pragma unroll
            for (int kb = 0; kb < 4; ++kb)
#pragma unroll
                for (int r = 0; r < 4; ++r)
                    p[kb][r] = __builtin_exp2f(st[kb][r]);
        }
#pragma unroll
        for (int kb = 0; kb < 4; ++kb)
#pragma unroll
            for (int r = 0; r < 4; ++r) lrow += p[kb][r];

#pragma unroll
        for (int kb = 0; kb < 4; ++kb) {
            uint2 u;
            u.x = cvtpk(p[kb][0], p[kb][1]);
            u.y = cvtpk(p[kb][2], p[kb][3]);
            *(uint2*)(myP + pW + kb * 32) = u;
        }
        asm volatile("s_waitcnt lgkmcnt(0)" ::: "memory");
        bf16x8 pf[2];
        pf[0] = *(const bf16x8*)(myP + pR);
        pf[1] = *(const bf16x8*)(myP + pR + 64);

        __builtin_amdgcn_s_setprio(1);
#pragma unroll
        for (int db = 0; db < 8; ++db) {
#pragma unroll
            for (int kc2 = 0; kc2 < 2; ++kc2) {
                bf16x8 vf = *(const bf16x8*)(cV + db * 2048 + vOff[kc2]);
                accO[db] = mfma16(vf, pf[kc2], accO[db]);
            }
        }
        __builtin_amdgcn_s_setprio(0);
    }
    epilogue();
}

// ---------------------------------------------------------------------------
extern "C" void kernel_launch(void* const* d_in, const int* in_sizes, int n_in,
                              void* d_out, int out_size, void* d_ws, size_t ws_size,
                              hipStream_t stream) {
    const float* hidden = (const float*)d_in[0];
    const float* Wq = (const float*)d_in[1];
    const float* Wk = (const float*)d_in[2];
    const float* Wv = (const float*)d_in[3];
    const float* Wo = (const float*)d_in[4];
    const float* qw = (const float*)d_in[5];
    const float* kw = (const float*)d_in[6];
    float* out = (float*)d_out;

    char* ws = (char*)d_ws;
    size_t off = 0;
    auto alloc = [&](size_t bytes) { char* p = ws + off; off += (bytes + 255) & ~255ull; return p; };
    __hip_bfloat16* Wq_t = (__hip_bfloat16*)alloc((size_t)HS_ * NH_ * HD_ * 2);   // 8 MB
    __hip_bfloat16* Wk_t = (__hip_bfloat16*)alloc((size_t)HS_ * NKV_ * HD_ * 2);  // 2 MB (contiguous after Wq_t)
    __hip_bfloat16* Wv_t = (__hip_bfloat16*)alloc((size_t)HS_ * NKV_ * HD_ * 2);  // 2 MB (contiguous after Wk_t)
    __hip_bfloat16* Wo_t = (__hip_bfloat16*)alloc((size_t)HS_ * NH_ * HD_ * 2);   // 8 MB
    __hip_bfloat16* A_h  = (__hip_bfloat16*)alloc((size_t)B_ * L_ * HS_ * 2);     // 16 MB; reused as attn_bf
    float* kv_f32 = (float*)alloc((size_t)B_ * L_ * 1024 * 4);                    // 16 MB [M,1024] = K|V
    __hip_bfloat16* q_bf  = (__hip_bfloat16*)alloc((size_t)B_ * L_ * NH_ * HD_ * 2);
    __hip_bfloat16* k_bf  = (__hip_bfloat16*)alloc((size_t)B_ * L_ * NKV_ * HD_ * 2);
    __hip_bfloat16* vt_bf = (__hip_bfloat16*)alloc((size_t)B_ * NKV_ * HD_ * L_ * 2);
    float* q_f32 = out;                     // reuse d_out as pre-norm Q scratch
    __hip_bfloat16* attn_bf = A_h;

    const int M = B_ * L_;

    // 1) hidden cvt + all 4 weight transposes in one launch
    fused_prep<<<18432, 256, 0, stream>>>(hidden, A_h, Wq, Wq_t, Wk, Wk_t, Wv, Wv_t, Wo, Wo_t);
    // 2) fused QKV projection: Bt rows 0..2047 = Wq_t, 2048..3071 = Wk_t|Wv_t
    gemm8_bf16<<<dim3(M / 256, 3072 / 256), 512, 0, stream>>>(
        A_h, Wq_t, q_f32, kv_f32, 3072, 2048);
    // 3) Q-norm-rope + K-norm-rope + V transpose in one launch
    fused_norm_v<<<22528, 256, 0, stream>>>(q_f32, q_bf, kv_f32, k_bf, vt_bf, qw, kw);
    // 4) attention
    flash_attn<<<dim3(16, NH_, B_), 256, 0, stream>>>(q_bf, k_bf, vt_bf, attn_bf);
    // 5) O projection
    gemm_o<<<dim3(M / 128, 2048 / 256), 512, 0, stream>>>(attn_bf, Wo_t, out);
}